// Round 4
// baseline (222.663 us; speedup 1.0000x reference)
//
#include <hip/hip_runtime.h>
#include <hip/hip_bf16.h>

#define N_NODES 50000
#define E_EDGES 800000
#define IN_DIM  256
#define HID     128
#define OUT_DIM 16

#define NBUCK 391    // ceil(50000/128) buckets of 128 nodes (dst>>7)
#define NBLK  128    // blocks for bucket phases A/C
#define P2CAP 4096   // max edges per bucket (mean 2046, sigma ~45)
#define GB1   391    // gemm1 blocks: ceil(50000/128)

using frag_ab = __attribute__((ext_vector_type(8))) short;  // 8 bf16
using frag_cd = __attribute__((ext_vector_type(4))) float;  // 4 fp32

static __device__ inline short f2bf(float f) {
    union { float f; unsigned u; } v; v.f = f;
    unsigned r = (v.u + 0x7fffu + ((v.u >> 16) & 1u)) >> 16;
    return (short)r;
}
static __device__ inline float bflo(unsigned u) {
    union { unsigned u; float f; } v; v.u = u << 16; return v.f;
}
static __device__ inline float bfhi(unsigned u) {
    union { unsigned u; float f; } v; v.u = u & 0xffff0000u; return v.f;
}
static __device__ inline unsigned packbf(float a, float b) {
    return (unsigned)(unsigned short)f2bf(a) | ((unsigned)(unsigned short)f2bf(b) << 16);
}

// ===== K1: csr_a bucket histogram + per-node degree atomics || w2t ==========
// blocks [0, NBLK): LDS bucket hist -> cnt_bb; global atomicAdd -> deg[node]
// block  NBLK: W2 -> column-major bf16 (w2t[n][k])
// NOTE: edge partition (bb*512 stride NBLK*512) must match csr_c2 exactly.
__global__ __launch_bounds__(512) void k1_csra_deg(const int4* __restrict__ dst4,
                                                   const float* __restrict__ W2,
                                                   int* __restrict__ cnt_bb,
                                                   int* __restrict__ deg,
                                                   short* __restrict__ w2t) {
    int tid = threadIdx.x;
    if (blockIdx.x == NBLK) {
        // ---- w2t: W2 [128x16] f32 -> col-major bf16 [16][128]
        int n0 = tid >> 5, k0 = (tid & 31) * 4;
#pragma unroll
        for (int i = 0; i < 4; ++i)
            w2t[n0 * HID + k0 + i] = f2bf(W2[(k0 + i) * OUT_DIM + n0]);
        return;
    }
    __shared__ int hist[NBUCK];
    int bb = blockIdx.x;
    for (int i = tid; i < NBUCK; i += 512) hist[i] = 0;
    __syncthreads();
    for (int i = bb * 512 + tid; i < E_EDGES / 4; i += NBLK * 512) {
        int4 d = dst4[i];
        atomicAdd(&hist[d.x >> 7], 1);
        atomicAdd(&hist[d.y >> 7], 1);
        atomicAdd(&hist[d.z >> 7], 1);
        atomicAdd(&hist[d.w >> 7], 1);
        atomicAdd(&deg[d.x], 1);
        atomicAdd(&deg[d.y], 1);
        atomicAdd(&deg[d.z], 1);
        atomicAdd(&deg[d.w], 1);
    }
    __syncthreads();
    for (int i = tid; i < NBUCK; i += 512) cnt_bb[i * NBLK + bb] = hist[i];
}

// ===== K2: gemm1 (inline W1 transform, dinv-scaled h1s, writes dinv) || b1 ==
// blocks [0, GB1): h1s = bf16((x @ W1) * dinv), dinv = rsqrt(deg+1)
// blocks [GB1, GB1+NBUCK): per-bucket exclusive scan over blocks (csr_b1)
__global__ __launch_bounds__(512) void k2_gemm1_b1(const float* __restrict__ x,
                                                   const float* __restrict__ W1,
                                                   const int* __restrict__ deg,
                                                   int* __restrict__ cnt_bb,
                                                   int* __restrict__ btot,
                                                   float* __restrict__ dinv,
                                                   short* __restrict__ h1s) {
    __shared__ uint4 lwt[64 * 64];   // 64 KB (b1 blocks alias a small scan array)
    int tid = threadIdx.x;

    if (blockIdx.x >= GB1) {
        // ---- csr_b1 ported to 512 threads (only t<128 active on data)
        int* sm = (int*)lwt;
        int b = blockIdx.x - GB1, t = tid;
        int v = 0;
        if (t < NBLK) { v = cnt_bb[b * NBLK + t]; sm[t] = v; }
        __syncthreads();
        for (int o = 1; o < NBLK; o <<= 1) {
            int u = (t >= o && t < NBLK) ? sm[t - o] : 0;
            __syncthreads();
            if (t < NBLK) sm[t] += u;
            __syncthreads();
        }
        if (t < NBLK) cnt_bb[b * NBLK + t] = sm[t] - v;
        if (t == NBLK - 1) btot[b] = sm[t];
        return;
    }

    // ---- gemm1: build fragment-major bf16 W1 tile in LDS directly from f32 W1
#pragma unroll
    for (int it = 0; it < 8; ++it) {
        int j = it * 512 + tid;
        int f = j >> 6, lane_ = j & 63;
        int kt = f >> 3, tt = f & 7;
        int mm = lane_ & 15, qq = lane_ >> 4;
        int c = tt * 16 + mm;
        int k0 = kt * 32 + qq * 8;
        unsigned p[4];
#pragma unroll
        for (int i = 0; i < 4; ++i)
            p[i] = packbf(W1[(k0 + 2 * i) * HID + c], W1[(k0 + 2 * i + 1) * HID + c]);
        uint4 v; v.x = p[0]; v.y = p[1]; v.z = p[2]; v.w = p[3];
        lwt[j] = v;
    }

    int wave = tid >> 6;
    int lane = tid & 63;
    int m = lane & 15;
    int q = lane >> 4;
    int row0 = blockIdx.x * 128 + wave * 16;
    int arow_idx = row0 + m;
    const float4* arow4 = (const float4*)(x + (size_t)(arow_idx < N_NODES ? arow_idx : 0) * IN_DIM);

    frag_ab a[8];
#pragma unroll
    for (int kt = 0; kt < 8; ++kt) {
        float4 f0 = arow4[kt * 8 + q * 2];
        float4 f1 = arow4[kt * 8 + q * 2 + 1];
        a[kt][0] = f2bf(f0.x); a[kt][1] = f2bf(f0.y); a[kt][2] = f2bf(f0.z); a[kt][3] = f2bf(f0.w);
        a[kt][4] = f2bf(f1.x); a[kt][5] = f2bf(f1.y); a[kt][6] = f2bf(f1.z); a[kt][7] = f2bf(f1.w);
    }

    frag_cd acc[8];
#pragma unroll
    for (int t = 0; t < 8; ++t) acc[t] = frag_cd{0.f, 0.f, 0.f, 0.f};

    __syncthreads();

#pragma unroll
    for (int kt = 0; kt < 8; ++kt) {
#pragma unroll
        for (int t = 0; t < 8; ++t) {
            frag_ab b = *(const frag_ab*)&lwt[(kt * 8 + t) * 64 + lane];
            acc[t] = __builtin_amdgcn_mfma_f32_16x16x32_bf16(a[kt], b, acc[t], 0, 0, 0);
        }
    }

    // dinv from degree; scale output rows; publish dinv table (round-0 shape)
    float dv[4];
#pragma unroll
    for (int r = 0; r < 4; ++r) {
        int orow = row0 + q * 4 + r;
        dv[r] = (orow < N_NODES) ? rsqrtf((float)(deg[orow] + 1)) : 0.f;
    }
    if (m == 0) {
#pragma unroll
        for (int r = 0; r < 4; ++r) {
            int orow = row0 + q * 4 + r;
            if (orow < N_NODES) dinv[orow] = dv[r];
        }
    }
#pragma unroll
    for (int t = 0; t < 8; ++t) {
#pragma unroll
        for (int r = 0; r < 4; ++r) {
            int orow = row0 + q * 4 + r;
            if (orow < N_NODES)
                h1s[(size_t)orow * HID + t * 16 + m] = f2bf(acc[t][r] * dv[r]);
        }
    }
}

// ========== K3: csr_c with inline bucket-base scan (proven, unchanged) ======
__global__ __launch_bounds__(512) void csr_c2(const int4* __restrict__ src4,
                                              const int4* __restrict__ dst4,
                                              const int* __restrict__ cnt_bb,
                                              const int* __restrict__ btot,
                                              int* __restrict__ bbase,
                                              unsigned* __restrict__ tmp) {
    __shared__ int run[NBUCK];
    __shared__ int sc[512];
    int t = threadIdx.x;
    int v = (t < NBUCK) ? btot[t] : 0;
    sc[t] = v;
    __syncthreads();
    for (int o = 1; o < 512; o <<= 1) {
        int u = (t >= o) ? sc[t - o] : 0;
        __syncthreads();
        sc[t] += u;
        __syncthreads();
    }
    if (t < NBUCK) {
        int exc = sc[t] - v;
        run[t] = exc + cnt_bb[t * NBLK + blockIdx.x];
        if (blockIdx.x == 0) bbase[t] = exc;
    }
    if (blockIdx.x == 0 && t == 511) bbase[NBUCK] = sc[511];
    __syncthreads();
    for (int i = blockIdx.x * 512 + t; i < E_EDGES / 4; i += NBLK * 512) {
        int4 d = dst4[i];
        int4 s = src4[i];
        int p0 = atomicAdd(&run[d.x >> 7], 1);
        tmp[p0] = (unsigned)s.x | ((unsigned)(d.x & 127) << 17);
        int p1 = atomicAdd(&run[d.y >> 7], 1);
        tmp[p1] = (unsigned)s.y | ((unsigned)(d.y & 127) << 17);
        int p2 = atomicAdd(&run[d.z >> 7], 1);
        tmp[p2] = (unsigned)s.z | ((unsigned)(d.z & 127) << 17);
        int p3 = atomicAdd(&run[d.w >> 7], 1);
        tmp[p3] = (unsigned)s.w | ((unsigned)(d.w & 127) << 17);
    }
}

// ===== K4: within-bucket counting sort -> rowptr/ssrc (no dinv, no scale) ===
__global__ __launch_bounds__(256) void csr_p2(const unsigned* __restrict__ tmp,
                                              const int* __restrict__ bbase,
                                              int* __restrict__ rowptr,
                                              int* __restrict__ ssrc) {
    __shared__ unsigned ed[P2CAP];
    __shared__ int cnt[128];
    __shared__ int off[128];
    int b = blockIdx.x, t = threadIdx.x;
    int base = bbase[b];
    int m = bbase[b + 1] - base;
    if (m > P2CAP) m = P2CAP;
    if (t < 128) cnt[t] = 0;
    __syncthreads();
    for (int i = t; i < m; i += 256) {
        unsigned v = tmp[base + i];
        ed[i] = v;
        atomicAdd(&cnt[v >> 17], 1);
    }
    __syncthreads();
    if (t < 128) off[t] = cnt[t];
    __syncthreads();
    for (int o = 1; o < 128; o <<= 1) {
        int u = (t >= o && t < 128) ? off[t - o] : 0;
        __syncthreads();
        if (t < 128) off[t] += u;
        __syncthreads();
    }
    if (t < 128) {
        int node = b * 128 + t;
        int ex = off[t] - cnt[t];
        if (node < N_NODES) rowptr[node] = base + ex;
        off[t] = ex;
    }
    if (b == NBUCK - 1 && t == 0) rowptr[N_NODES] = E_EDGES;
    __syncthreads();
    for (int i = t; i < m; i += 256) {
        unsigned v = ed[i];
        int p = atomicAdd(&off[v >> 17], 1);
        ssrc[base + p] = (int)(v & 0x1FFFF);
    }
}

// ===== K5: layer-1 pull (PROVEN, byte-identical gather loop) ================
__global__ __launch_bounds__(256) void agg1_pull(const short* __restrict__ h1s,
                                                 const float* __restrict__ dinv,
                                                 const float* __restrict__ b1,
                                                 const int* __restrict__ rowptr,
                                                 const int* __restrict__ ssrc,
                                                 uint4* __restrict__ out1) {
    int wave = threadIdx.x >> 6;
    int lane = threadIdx.x & 63;
    int node = __builtin_amdgcn_readfirstlane(blockIdx.x * 4 + wave);
    if (node >= N_NODES) return;
    int eo = lane >> 4;       // edge slot in quad
    int g  = lane & 15;       // feature octet

    int lo = rowptr[node], hi = rowptr[node + 1];
    float dd = dinv[node];
    float a0 = 0.f, a1 = 0.f, a2 = 0.f, a3 = 0.f;
    float a4 = 0.f, a5 = 0.f, a6 = 0.f, a7 = 0.f;

    if (eo == 0) {   // self-loop row
        uint4 u = *(const uint4*)(h1s + (size_t)node * HID + g * 8);
        a0 = bflo(u.x); a1 = bfhi(u.x); a2 = bflo(u.y); a3 = bfhi(u.y);
        a4 = bflo(u.z); a5 = bfhi(u.z); a6 = bflo(u.w); a7 = bfhi(u.w);
    }

    int e = lo;
    for (; e + 16 <= hi; e += 16) {
        int s0 = ssrc[e + eo];
        int s1 = ssrc[e + 4 + eo];
        int s2 = ssrc[e + 8 + eo];
        int s3 = ssrc[e + 12 + eo];
        uint4 u0 = *(const uint4*)(h1s + (size_t)s0 * HID + g * 8);
        uint4 u1 = *(const uint4*)(h1s + (size_t)s1 * HID + g * 8);
        uint4 u2 = *(const uint4*)(h1s + (size_t)s2 * HID + g * 8);
        uint4 u3 = *(const uint4*)(h1s + (size_t)s3 * HID + g * 8);
        a0 += bflo(u0.x); a1 += bfhi(u0.x); a2 += bflo(u0.y); a3 += bfhi(u0.y);
        a4 += bflo(u0.z); a5 += bfhi(u0.z); a6 += bflo(u0.w); a7 += bfhi(u0.w);
        a0 += bflo(u1.x); a1 += bfhi(u1.x); a2 += bflo(u1.y); a3 += bfhi(u1.y);
        a4 += bflo(u1.z); a5 += bfhi(u1.z); a6 += bflo(u1.w); a7 += bfhi(u1.w);
        a0 += bflo(u2.x); a1 += bfhi(u2.x); a2 += bflo(u2.y); a3 += bfhi(u2.y);
        a4 += bflo(u2.z); a5 += bfhi(u2.z); a6 += bflo(u2.w); a7 += bfhi(u2.w);
        a0 += bflo(u3.x); a1 += bfhi(u3.x); a2 += bflo(u3.y); a3 += bfhi(u3.y);
        a4 += bflo(u3.z); a5 += bfhi(u3.z); a6 += bflo(u3.w); a7 += bfhi(u3.w);
    }
    for (; e + 4 <= hi; e += 4) {
        int s = ssrc[e + eo];
        uint4 u = *(const uint4*)(h1s + (size_t)s * HID + g * 8);
        a0 += bflo(u.x); a1 += bfhi(u.x); a2 += bflo(u.y); a3 += bfhi(u.y);
        a4 += bflo(u.z); a5 += bfhi(u.z); a6 += bflo(u.w); a7 += bfhi(u.w);
    }
    if (eo < hi - e) {
        int s = ssrc[e + eo];
        uint4 u = *(const uint4*)(h1s + (size_t)s * HID + g * 8);
        a0 += bflo(u.x); a1 += bfhi(u.x); a2 += bflo(u.y); a3 += bfhi(u.y);
        a4 += bflo(u.z); a5 += bfhi(u.z); a6 += bflo(u.w); a7 += bfhi(u.w);
    }

    a0 += __shfl_xor(a0, 16); a1 += __shfl_xor(a1, 16);
    a2 += __shfl_xor(a2, 16); a3 += __shfl_xor(a3, 16);
    a4 += __shfl_xor(a4, 16); a5 += __shfl_xor(a5, 16);
    a6 += __shfl_xor(a6, 16); a7 += __shfl_xor(a7, 16);
    a0 += __shfl_xor(a0, 32); a1 += __shfl_xor(a1, 32);
    a2 += __shfl_xor(a2, 32); a3 += __shfl_xor(a3, 32);
    a4 += __shfl_xor(a4, 32); a5 += __shfl_xor(a5, 32);
    a6 += __shfl_xor(a6, 32); a7 += __shfl_xor(a7, 32);

    if (eo == 0) {
        float4 bA = *(const float4*)(b1 + g * 8);
        float4 bB = *(const float4*)(b1 + g * 8 + 4);
        float o0 = fmaxf(fmaf(dd, a0, bA.x), 0.f);
        float o1 = fmaxf(fmaf(dd, a1, bA.y), 0.f);
        float o2 = fmaxf(fmaf(dd, a2, bA.z), 0.f);
        float o3 = fmaxf(fmaf(dd, a3, bA.w), 0.f);
        float o4 = fmaxf(fmaf(dd, a4, bB.x), 0.f);
        float o5 = fmaxf(fmaf(dd, a5, bB.y), 0.f);
        float o6 = fmaxf(fmaf(dd, a6, bB.z), 0.f);
        float o7 = fmaxf(fmaf(dd, a7, bB.w), 0.f);
        uint4 st;
        st.x = packbf(o0, o1); st.y = packbf(o2, o3);
        st.z = packbf(o4, o5); st.w = packbf(o6, o7);
        out1[(size_t)node * 16 + g] = st;
    }
}

// ===== K6: layer-2 transform via MFMA (proven, unchanged) ===================
__global__ __launch_bounds__(256) void gemm2_mfma(const short* __restrict__ out1,
                                                  const short* __restrict__ w2t,
                                                  const float* __restrict__ dinv,
                                                  short* __restrict__ h2s) {
    int wave = threadIdx.x >> 6;
    int lane = threadIdx.x & 63;
    int m = lane & 15;
    int q = lane >> 4;
    int row0 = blockIdx.x * 64 + wave * 16;
    int arow = row0 + m;
    if (arow >= N_NODES) arow = N_NODES - 1;   // clamp loads
    const short* ap = out1 + (size_t)arow * HID + q * 8;
    const short* bp = w2t + m * HID + q * 8;

    frag_cd acc = frag_cd{0.f, 0.f, 0.f, 0.f};
#pragma unroll
    for (int kt = 0; kt < 4; ++kt) {
        frag_ab a = *(const frag_ab*)(ap + kt * 32);
        frag_ab b = *(const frag_ab*)(bp + kt * 32);
        acc = __builtin_amdgcn_mfma_f32_16x16x32_bf16(a, b, acc, 0, 0, 0);
    }
#pragma unroll
    for (int r = 0; r < 4; ++r) {
        int row = row0 + q * 4 + r;
        if (row < N_NODES)
            h2s[(size_t)row * OUT_DIM + m] = f2bf(acc[r] * dinv[row]);
    }
}

// ===== K7: layer-2 pull + bias + log_softmax (proven, unchanged) ============
__global__ __launch_bounds__(256) void agg2_pull(const unsigned* __restrict__ h2s,
                                                 const float* __restrict__ dinv,
                                                 const float* __restrict__ b2,
                                                 const int* __restrict__ rowptr,
                                                 const int* __restrict__ ssrc,
                                                 float* __restrict__ out) {
    int wave = threadIdx.x >> 6;
    int lane = threadIdx.x & 63;
    int node = __builtin_amdgcn_readfirstlane(blockIdx.x * 4 + wave);
    if (node >= N_NODES) return;
    int eo = lane >> 3;
    int g  = lane & 7;

    int lo = rowptr[node], hi = rowptr[node + 1];
    float a0 = 0.f, a1 = 0.f;
    if (eo == 0) {
        unsigned u = h2s[(size_t)node * 8 + g];
        a0 = bflo(u); a1 = bfhi(u);
    }
    int e = lo;
    for (; e + 16 <= hi; e += 16) {
        int s0 = ssrc[e + eo];
        int s1 = ssrc[e + 8 + eo];
        unsigned u0 = h2s[(size_t)s0 * 8 + g];
        unsigned u1 = h2s[(size_t)s1 * 8 + g];
        a0 += bflo(u0); a1 += bfhi(u0);
        a0 += bflo(u1); a1 += bfhi(u1);
    }
    for (; e + 8 <= hi; e += 8) {
        int s = ssrc[e + eo];
        unsigned u = h2s[(size_t)s * 8 + g];
        a0 += bflo(u); a1 += bfhi(u);
    }
    if (eo < hi - e) {
        int s = ssrc[e + eo];
        unsigned u = h2s[(size_t)s * 8 + g];
        a0 += bflo(u); a1 += bfhi(u);
    }

    a0 += __shfl_xor(a0, 8);  a1 += __shfl_xor(a1, 8);
    a0 += __shfl_xor(a0, 16); a1 += __shfl_xor(a1, 16);
    a0 += __shfl_xor(a0, 32); a1 += __shfl_xor(a1, 32);

    float dd = dinv[node];
    float2 bb = *(const float2*)(b2 + 2 * g);
    float v0 = fmaf(dd, a0, bb.x);
    float v1 = fmaf(dd, a1, bb.y);

    float m = fmaxf(v0, v1);
#pragma unroll
    for (int msk = 1; msk < 8; msk <<= 1) m = fmaxf(m, __shfl_xor(m, msk));
    float s2 = __expf(v0 - m) + __expf(v1 - m);
#pragma unroll
    for (int msk = 1; msk < 8; msk <<= 1) s2 += __shfl_xor(s2, msk);
    float lse = m + __logf(s2);
    if (eo == 0) {
        float2 o; o.x = v0 - lse; o.y = v1 - lse;
        *(float2*)(out + (size_t)node * OUT_DIM + 2 * g) = o;
    }
}

extern "C" void kernel_launch(void* const* d_in, const int* in_sizes, int n_in,
                              void* d_out, int out_size, void* d_ws, size_t ws_size,
                              hipStream_t stream) {
    const float* x  = (const float*)d_in[0];
    const int*   ei = (const int*)d_in[1];
    const float* W1 = (const float*)d_in[2];
    const float* b1 = (const float*)d_in[3];
    const float* W2 = (const float*)d_in[4];
    const float* b2 = (const float*)d_in[5];
    float* out = (float*)d_out;

    const int n = N_NODES;
    const int e = E_EDGES;
    const int* srcp = ei;        // edge_index[0]
    const int* dstp = ei + e;    // edge_index[1]

    // workspace layout
    char* w = (char*)d_ws;
    int*      cnt_bb = (int*)w;        w += (size_t)NBUCK * NBLK * 4;
    int*      btot   = (int*)w;        w += (size_t)NBUCK * 4;
    int*      bbase  = (int*)w;        w += (size_t)(NBUCK + 1) * 4;
    int*      deg    = (int*)w;        w += (size_t)n * 4;
    int*      rowptr = (int*)w;        w += (size_t)(n + 1) * 4;
    float*    dinv   = (float*)w;      w += (size_t)n * 4;
    unsigned* tmp    = (unsigned*)w;   w += (size_t)e * 4;
    int*      ssrc   = (int*)w;        w += (size_t)e * 4;
    short*    w2t    = (short*)w;      w += (size_t)OUT_DIM * HID * 2;  // col-major bf16 W2
    short*    h1s    = (short*)w;      w += (size_t)n * HID * 2;     // bf16, scaled in gemm1
    short*    out1   = (short*)w;      w += (size_t)n * HID * 2;     // bf16 relu'd layer-1 out
    short*    h2s    = (short*)w;      w += (size_t)n * OUT_DIM * 2; // bf16

    auto blk = [](long long total, int b) { return (int)((total + b - 1) / b); };

    // K0: zero degree counters (capture-legal fill)
    hipMemsetAsync(deg, 0, (size_t)n * sizeof(int), stream);
    // K1: bucket histogram + per-node degrees || w2t transform
    k1_csra_deg<<<NBLK + 1, 512, 0, stream>>>((const int4*)dstp, W2, cnt_bb, deg, w2t);
    // K2: layer-1 GEMM with dinv epilogue (scaled h1s + dinv table) || b1 scan
    k2_gemm1_b1<<<GB1 + NBUCK, 512, 0, stream>>>(x, W1, deg, cnt_bb, btot, dinv, h1s);
    // K3: bucket scatter (inline bbase scan; block 0 publishes bbase)
    csr_c2<<<NBLK, 512, 0, stream>>>((const int4*)srcp, (const int4*)dstp,
                                     cnt_bb, btot, bbase, tmp);
    // K4: within-bucket sort -> rowptr/ssrc
    csr_p2<<<NBUCK, 256, 0, stream>>>(tmp, bbase, rowptr, ssrc);
    // K5: layer-1 aggregate + bias/ReLU -> out1 (bf16)
    agg1_pull<<<blk(n, 4), 256, 0, stream>>>(h1s, dinv, b1, rowptr, ssrc, (uint4*)out1);
    // K6: layer-2 dense transform (MFMA), pre-scaled by dinv
    gemm2_mfma<<<blk(n, 64), 256, 0, stream>>>(out1, w2t, dinv, h2s);
    // K7: layer-2 aggregate + bias + log_softmax
    agg2_pull<<<blk(n, 4), 256, 0, stream>>>((const unsigned*)h2s, dinv, b2,
                                             rowptr, ssrc, out);
}

// Round 5
// 217.081 us; speedup vs baseline: 1.0257x; 1.0257x over previous
//
#include <hip/hip_runtime.h>
#include <hip/hip_bf16.h>

#define N_NODES 50000
#define E_EDGES 800000
#define IN_DIM  256
#define HID     128
#define OUT_DIM 16

#define NBUCK 391    // ceil(50000/128) buckets of 128 nodes (dst>>7)
#define NBLK  128    // blocks for bucket phases A/C
#define P2CAP 4096   // max edges per bucket (mean 2046, sigma ~45)
#define GB1   391    // gemm1 blocks: ceil(50000/128)
#define NCHUNK 98    // hscale chunks: ceil(50000/512)

using frag_ab = __attribute__((ext_vector_type(8))) short;  // 8 bf16
using frag_cd = __attribute__((ext_vector_type(4))) float;  // 4 fp32

static __device__ inline short f2bf(float f) {
    union { float f; unsigned u; } v; v.f = f;
    unsigned r = (v.u + 0x7fffu + ((v.u >> 16) & 1u)) >> 16;
    return (short)r;
}
static __device__ inline float bflo(unsigned u) {
    union { unsigned u; float f; } v; v.u = u << 16; return v.f;
}
static __device__ inline float bfhi(unsigned u) {
    union { unsigned u; float f; } v; v.u = u & 0xffff0000u; return v.f;
}
static __device__ inline unsigned packbf(float a, float b) {
    return (unsigned)(unsigned short)f2bf(a) | ((unsigned)(unsigned short)f2bf(b) << 16);
}

// ===== K1: gemm1 (UNSCALED h1s, starts at t=0) || csr_a+deg || w2t ==========
// blocks [0, GB1): layer-1 dense transform, h1s = bf16(x @ W1)  (no dinv)
// blocks [GB1, GB1+NBLK): dst bucket histogram -> cnt_bb; deg atomics
// block  GB1+NBLK: W2 -> column-major bf16 (w2t[n][k])
__global__ __launch_bounds__(512) void k1_gemm1_csra(const float* __restrict__ x,
                                                     const float* __restrict__ W1,
                                                     const int4* __restrict__ dst4,
                                                     const float* __restrict__ W2,
                                                     int* __restrict__ cnt_bb,
                                                     int* __restrict__ deg,
                                                     short* __restrict__ w2t,
                                                     short* __restrict__ h1s) {
    __shared__ uint4 lwt[64 * 64];   // 64 KB (aliased as int hist[] for csr_a blocks)
    int tid = threadIdx.x;

    if (blockIdx.x == GB1 + NBLK) {
        // ---- w2t: W2 [128x16] f32 -> col-major bf16 [16][128]
        int n0 = tid >> 5, k0 = (tid & 31) * 4;
#pragma unroll
        for (int i = 0; i < 4; ++i)
            w2t[n0 * HID + k0 + i] = f2bf(W2[(k0 + i) * OUT_DIM + n0]);
        return;
    }
    if (blockIdx.x >= GB1) {
        // ---- csr_a + deg (proven r4 loop; partition must match csr_c2b!)
        int* hist = (int*)lwt;
        int bb = blockIdx.x - GB1;
        for (int i = tid; i < NBUCK; i += 512) hist[i] = 0;
        __syncthreads();
        for (int i = bb * 512 + tid; i < E_EDGES / 4; i += NBLK * 512) {
            int4 d = dst4[i];
            atomicAdd(&hist[d.x >> 7], 1);
            atomicAdd(&hist[d.y >> 7], 1);
            atomicAdd(&hist[d.z >> 7], 1);
            atomicAdd(&hist[d.w >> 7], 1);
            atomicAdd(&deg[d.x], 1);
            atomicAdd(&deg[d.y], 1);
            atomicAdd(&deg[d.z], 1);
            atomicAdd(&deg[d.w], 1);
        }
        __syncthreads();
        for (int i = tid; i < NBUCK; i += 512) cnt_bb[i * NBLK + bb] = hist[i];
        return;
    }

    // ---- gemm1: build fragment-major bf16 W1 tile in LDS directly from f32 W1
#pragma unroll
    for (int it = 0; it < 8; ++it) {
        int j = it * 512 + tid;
        int f = j >> 6, lane_ = j & 63;
        int kt = f >> 3, tt = f & 7;
        int mm = lane_ & 15, qq = lane_ >> 4;
        int c = tt * 16 + mm;
        int k0 = kt * 32 + qq * 8;
        unsigned p[4];
#pragma unroll
        for (int i = 0; i < 4; ++i)
            p[i] = packbf(W1[(k0 + 2 * i) * HID + c], W1[(k0 + 2 * i + 1) * HID + c]);
        uint4 v; v.x = p[0]; v.y = p[1]; v.z = p[2]; v.w = p[3];
        lwt[j] = v;
    }

    int wave = tid >> 6;
    int lane = tid & 63;
    int m = lane & 15;
    int q = lane >> 4;
    int row0 = blockIdx.x * 128 + wave * 16;
    int arow_idx = row0 + m;
    const float4* arow4 = (const float4*)(x + (size_t)(arow_idx < N_NODES ? arow_idx : 0) * IN_DIM);

    frag_ab a[8];
#pragma unroll
    for (int kt = 0; kt < 8; ++kt) {
        float4 f0 = arow4[kt * 8 + q * 2];
        float4 f1 = arow4[kt * 8 + q * 2 + 1];
        a[kt][0] = f2bf(f0.x); a[kt][1] = f2bf(f0.y); a[kt][2] = f2bf(f0.z); a[kt][3] = f2bf(f0.w);
        a[kt][4] = f2bf(f1.x); a[kt][5] = f2bf(f1.y); a[kt][6] = f2bf(f1.z); a[kt][7] = f2bf(f1.w);
    }

    frag_cd acc[8];
#pragma unroll
    for (int t = 0; t < 8; ++t) acc[t] = frag_cd{0.f, 0.f, 0.f, 0.f};

    __syncthreads();

#pragma unroll
    for (int kt = 0; kt < 8; ++kt) {
#pragma unroll
        for (int t = 0; t < 8; ++t) {
            frag_ab b = *(const frag_ab*)&lwt[(kt * 8 + t) * 64 + lane];
            acc[t] = __builtin_amdgcn_mfma_f32_16x16x32_bf16(a[kt], b, acc[t], 0, 0, 0);
        }
    }

#pragma unroll
    for (int t = 0; t < 8; ++t) {
#pragma unroll
        for (int r = 0; r < 4; ++r) {
            int orow = row0 + q * 4 + r;
            if (orow < N_NODES)
                h1s[(size_t)orow * HID + t * 16 + m] = f2bf(acc[t][r]);   // unscaled
        }
    }
}

// ===== K2: scatter with inline prefix (b1 folded)  ||  h1s scale + dinv =====
// blocks [0, NBLK): csr_c2b (proven r3 bench)
// blocks [NBLK, NBLK+NCHUNK): scale h1s rows by rsqrt(deg+1); write dinv
__global__ __launch_bounds__(512) void k2_scatter_scale(const int4* __restrict__ src4,
                                                        const int4* __restrict__ dst4,
                                                        const int* __restrict__ cnt_bb,
                                                        const int* __restrict__ deg,
                                                        int* __restrict__ bbase,
                                                        float* __restrict__ dinv,
                                                        short* __restrict__ h1s,
                                                        unsigned* __restrict__ tmp) {
    int t = threadIdx.x;
    if (blockIdx.x >= NBLK) {
        // ---- hscale: 512 nodes per block, p2s-proven coalesced word split
        int base_node = (blockIdx.x - NBLK) * 512;
        for (int idx = t; idx < 512 * 16; idx += 512) {
            int nl = idx >> 4;           // node within chunk
            int wd = idx & 15;           // uint4 word within 256B row
            int node = base_node + nl;
            if (node < N_NODES) {
                float dv = rsqrtf((float)(deg[node] + 1));
                if (wd == 0) dinv[node] = dv;
                uint4* p = (uint4*)(h1s + (size_t)node * HID) + wd;
                uint4 u = *p;
                u.x = packbf(dv * bflo(u.x), dv * bfhi(u.x));
                u.y = packbf(dv * bflo(u.y), dv * bfhi(u.y));
                u.z = packbf(dv * bflo(u.z), dv * bfhi(u.z));
                u.w = packbf(dv * bflo(u.w), dv * bfhi(u.w));
                *p = u;
            }
        }
        return;
    }
    // ---- csr_c2b: per-block prefix recompute + scatter
    __shared__ int run[NBUCK];
    __shared__ int sc[512];
    int j = blockIdx.x;
    int tot = 0, pre = 0;
    if (t < NBUCK) {
        const int4* row = (const int4*)(cnt_bb + t * NBLK);
#pragma unroll 4
        for (int b4 = 0; b4 < NBLK / 4; ++b4) {
            int4 c = row[b4];
            int b = b4 * 4;
            tot += c.x + c.y + c.z + c.w;
            pre += (b + 0 < j ? c.x : 0) + (b + 1 < j ? c.y : 0)
                 + (b + 2 < j ? c.z : 0) + (b + 3 < j ? c.w : 0);
        }
    }
    sc[t] = tot;
    __syncthreads();
    for (int o = 1; o < 512; o <<= 1) {
        int u = (t >= o) ? sc[t - o] : 0;
        __syncthreads();
        sc[t] += u;
        __syncthreads();
    }
    if (t < NBUCK) {
        int exc = sc[t] - tot;
        run[t] = exc + pre;
        if (j == 0) bbase[t] = exc;
    }
    if (j == 0 && t == 511) bbase[NBUCK] = sc[511];
    __syncthreads();
    for (int i = j * 512 + t; i < E_EDGES / 4; i += NBLK * 512) {
        int4 d = dst4[i];
        int4 s = src4[i];
        int p0 = atomicAdd(&run[d.x >> 7], 1);
        tmp[p0] = (unsigned)s.x | ((unsigned)(d.x & 127) << 17);
        int p1 = atomicAdd(&run[d.y >> 7], 1);
        tmp[p1] = (unsigned)s.y | ((unsigned)(d.y & 127) << 17);
        int p2 = atomicAdd(&run[d.z >> 7], 1);
        tmp[p2] = (unsigned)s.z | ((unsigned)(d.z & 127) << 17);
        int p3 = atomicAdd(&run[d.w >> 7], 1);
        tmp[p3] = (unsigned)s.w | ((unsigned)(d.w & 127) << 17);
    }
}

// ===== K3: within-bucket counting sort -> rowptr/ssrc (proven r4) ===========
__global__ __launch_bounds__(256) void csr_p2(const unsigned* __restrict__ tmp,
                                              const int* __restrict__ bbase,
                                              int* __restrict__ rowptr,
                                              int* __restrict__ ssrc) {
    __shared__ unsigned ed[P2CAP];
    __shared__ int cnt[128];
    __shared__ int off[128];
    int b = blockIdx.x, t = threadIdx.x;
    int base = bbase[b];
    int m = bbase[b + 1] - base;
    if (m > P2CAP) m = P2CAP;
    if (t < 128) cnt[t] = 0;
    __syncthreads();
    for (int i = t; i < m; i += 256) {
        unsigned v = tmp[base + i];
        ed[i] = v;
        atomicAdd(&cnt[v >> 17], 1);
    }
    __syncthreads();
    if (t < 128) off[t] = cnt[t];
    __syncthreads();
    for (int o = 1; o < 128; o <<= 1) {
        int u = (t >= o && t < 128) ? off[t - o] : 0;
        __syncthreads();
        if (t < 128) off[t] += u;
        __syncthreads();
    }
    if (t < 128) {
        int node = b * 128 + t;
        int ex = off[t] - cnt[t];
        if (node < N_NODES) rowptr[node] = base + ex;
        off[t] = ex;
    }
    if (b == NBUCK - 1 && t == 0) rowptr[N_NODES] = E_EDGES;
    __syncthreads();
    for (int i = t; i < m; i += 256) {
        unsigned v = ed[i];
        int p = atomicAdd(&off[v >> 17], 1);
        ssrc[base + p] = (int)(v & 0x1FFFF);
    }
}

// ===== K4: layer-1 pull (PROVEN, byte-identical gather loop) ================
__global__ __launch_bounds__(256) void agg1_pull(const short* __restrict__ h1s,
                                                 const float* __restrict__ dinv,
                                                 const float* __restrict__ b1,
                                                 const int* __restrict__ rowptr,
                                                 const int* __restrict__ ssrc,
                                                 uint4* __restrict__ out1) {
    int wave = threadIdx.x >> 6;
    int lane = threadIdx.x & 63;
    int node = __builtin_amdgcn_readfirstlane(blockIdx.x * 4 + wave);
    if (node >= N_NODES) return;
    int eo = lane >> 4;       // edge slot in quad
    int g  = lane & 15;       // feature octet

    int lo = rowptr[node], hi = rowptr[node + 1];
    float dd = dinv[node];
    float a0 = 0.f, a1 = 0.f, a2 = 0.f, a3 = 0.f;
    float a4 = 0.f, a5 = 0.f, a6 = 0.f, a7 = 0.f;

    if (eo == 0) {   // self-loop row
        uint4 u = *(const uint4*)(h1s + (size_t)node * HID + g * 8);
        a0 = bflo(u.x); a1 = bfhi(u.x); a2 = bflo(u.y); a3 = bfhi(u.y);
        a4 = bflo(u.z); a5 = bfhi(u.z); a6 = bflo(u.w); a7 = bfhi(u.w);
    }

    int e = lo;
    for (; e + 16 <= hi; e += 16) {
        int s0 = ssrc[e + eo];
        int s1 = ssrc[e + 4 + eo];
        int s2 = ssrc[e + 8 + eo];
        int s3 = ssrc[e + 12 + eo];
        uint4 u0 = *(const uint4*)(h1s + (size_t)s0 * HID + g * 8);
        uint4 u1 = *(const uint4*)(h1s + (size_t)s1 * HID + g * 8);
        uint4 u2 = *(const uint4*)(h1s + (size_t)s2 * HID + g * 8);
        uint4 u3 = *(const uint4*)(h1s + (size_t)s3 * HID + g * 8);
        a0 += bflo(u0.x); a1 += bfhi(u0.x); a2 += bflo(u0.y); a3 += bfhi(u0.y);
        a4 += bflo(u0.z); a5 += bfhi(u0.z); a6 += bflo(u0.w); a7 += bfhi(u0.w);
        a0 += bflo(u1.x); a1 += bfhi(u1.x); a2 += bflo(u1.y); a3 += bfhi(u1.y);
        a4 += bflo(u1.z); a5 += bfhi(u1.z); a6 += bflo(u1.w); a7 += bfhi(u1.w);
        a0 += bflo(u2.x); a1 += bfhi(u2.x); a2 += bflo(u2.y); a3 += bfhi(u2.y);
        a4 += bflo(u2.z); a5 += bfhi(u2.z); a6 += bflo(u2.w); a7 += bfhi(u2.w);
        a0 += bflo(u3.x); a1 += bfhi(u3.x); a2 += bflo(u3.y); a3 += bfhi(u3.y);
        a4 += bflo(u3.z); a5 += bfhi(u3.z); a6 += bflo(u3.w); a7 += bfhi(u3.w);
    }
    for (; e + 4 <= hi; e += 4) {
        int s = ssrc[e + eo];
        uint4 u = *(const uint4*)(h1s + (size_t)s * HID + g * 8);
        a0 += bflo(u.x); a1 += bfhi(u.x); a2 += bflo(u.y); a3 += bfhi(u.y);
        a4 += bflo(u.z); a5 += bfhi(u.z); a6 += bflo(u.w); a7 += bfhi(u.w);
    }
    if (eo < hi - e) {
        int s = ssrc[e + eo];
        uint4 u = *(const uint4*)(h1s + (size_t)s * HID + g * 8);
        a0 += bflo(u.x); a1 += bfhi(u.x); a2 += bflo(u.y); a3 += bfhi(u.y);
        a4 += bflo(u.z); a5 += bfhi(u.z); a6 += bflo(u.w); a7 += bfhi(u.w);
    }

    a0 += __shfl_xor(a0, 16); a1 += __shfl_xor(a1, 16);
    a2 += __shfl_xor(a2, 16); a3 += __shfl_xor(a3, 16);
    a4 += __shfl_xor(a4, 16); a5 += __shfl_xor(a5, 16);
    a6 += __shfl_xor(a6, 16); a7 += __shfl_xor(a7, 16);
    a0 += __shfl_xor(a0, 32); a1 += __shfl_xor(a1, 32);
    a2 += __shfl_xor(a2, 32); a3 += __shfl_xor(a3, 32);
    a4 += __shfl_xor(a4, 32); a5 += __shfl_xor(a5, 32);
    a6 += __shfl_xor(a6, 32); a7 += __shfl_xor(a7, 32);

    if (eo == 0) {
        float4 bA = *(const float4*)(b1 + g * 8);
        float4 bB = *(const float4*)(b1 + g * 8 + 4);
        float o0 = fmaxf(fmaf(dd, a0, bA.x), 0.f);
        float o1 = fmaxf(fmaf(dd, a1, bA.y), 0.f);
        float o2 = fmaxf(fmaf(dd, a2, bA.z), 0.f);
        float o3 = fmaxf(fmaf(dd, a3, bA.w), 0.f);
        float o4 = fmaxf(fmaf(dd, a4, bB.x), 0.f);
        float o5 = fmaxf(fmaf(dd, a5, bB.y), 0.f);
        float o6 = fmaxf(fmaf(dd, a6, bB.z), 0.f);
        float o7 = fmaxf(fmaf(dd, a7, bB.w), 0.f);
        uint4 st;
        st.x = packbf(o0, o1); st.y = packbf(o2, o3);
        st.z = packbf(o4, o5); st.w = packbf(o6, o7);
        out1[(size_t)node * 16 + g] = st;
    }
}

// ===== K5: layer-2 transform via MFMA (proven, unchanged) ===================
__global__ __launch_bounds__(256) void gemm2_mfma(const short* __restrict__ out1,
                                                  const short* __restrict__ w2t,
                                                  const float* __restrict__ dinv,
                                                  short* __restrict__ h2s) {
    int wave = threadIdx.x >> 6;
    int lane = threadIdx.x & 63;
    int m = lane & 15;
    int q = lane >> 4;
    int row0 = blockIdx.x * 64 + wave * 16;
    int arow = row0 + m;
    if (arow >= N_NODES) arow = N_NODES - 1;   // clamp loads
    const short* ap = out1 + (size_t)arow * HID + q * 8;
    const short* bp = w2t + m * HID + q * 8;

    frag_cd acc = frag_cd{0.f, 0.f, 0.f, 0.f};
#pragma unroll
    for (int kt = 0; kt < 4; ++kt) {
        frag_ab a = *(const frag_ab*)(ap + kt * 32);
        frag_ab b = *(const frag_ab*)(bp + kt * 32);
        acc = __builtin_amdgcn_mfma_f32_16x16x32_bf16(a, b, acc, 0, 0, 0);
    }
#pragma unroll
    for (int r = 0; r < 4; ++r) {
        int row = row0 + q * 4 + r;
        if (row < N_NODES)
            h2s[(size_t)row * OUT_DIM + m] = f2bf(acc[r] * dinv[row]);
    }
}

// ===== K6: layer-2 pull + bias + log_softmax (proven, unchanged) ============
__global__ __launch_bounds__(256) void agg2_pull(const unsigned* __restrict__ h2s,
                                                 const float* __restrict__ dinv,
                                                 const float* __restrict__ b2,
                                                 const int* __restrict__ rowptr,
                                                 const int* __restrict__ ssrc,
                                                 float* __restrict__ out) {
    int wave = threadIdx.x >> 6;
    int lane = threadIdx.x & 63;
    int node = __builtin_amdgcn_readfirstlane(blockIdx.x * 4 + wave);
    if (node >= N_NODES) return;
    int eo = lane >> 3;
    int g  = lane & 7;

    int lo = rowptr[node], hi = rowptr[node + 1];
    float a0 = 0.f, a1 = 0.f;
    if (eo == 0) {
        unsigned u = h2s[(size_t)node * 8 + g];
        a0 = bflo(u); a1 = bfhi(u);
    }
    int e = lo;
    for (; e + 16 <= hi; e += 16) {
        int s0 = ssrc[e + eo];
        int s1 = ssrc[e + 8 + eo];
        unsigned u0 = h2s[(size_t)s0 * 8 + g];
        unsigned u1 = h2s[(size_t)s1 * 8 + g];
        a0 += bflo(u0); a1 += bfhi(u0);
        a0 += bflo(u1); a1 += bfhi(u1);
    }
    for (; e + 8 <= hi; e += 8) {
        int s = ssrc[e + eo];
        unsigned u = h2s[(size_t)s * 8 + g];
        a0 += bflo(u); a1 += bfhi(u);
    }
    if (eo < hi - e) {
        int s = ssrc[e + eo];
        unsigned u = h2s[(size_t)s * 8 + g];
        a0 += bflo(u); a1 += bfhi(u);
    }

    a0 += __shfl_xor(a0, 8);  a1 += __shfl_xor(a1, 8);
    a0 += __shfl_xor(a0, 16); a1 += __shfl_xor(a1, 16);
    a0 += __shfl_xor(a0, 32); a1 += __shfl_xor(a1, 32);

    float dd = dinv[node];
    float2 bb = *(const float2*)(b2 + 2 * g);
    float v0 = fmaf(dd, a0, bb.x);
    float v1 = fmaf(dd, a1, bb.y);

    float m = fmaxf(v0, v1);
#pragma unroll
    for (int msk = 1; msk < 8; msk <<= 1) m = fmaxf(m, __shfl_xor(m, msk));
    float s2 = __expf(v0 - m) + __expf(v1 - m);
#pragma unroll
    for (int msk = 1; msk < 8; msk <<= 1) s2 += __shfl_xor(s2, msk);
    float lse = m + __logf(s2);
    if (eo == 0) {
        float2 o; o.x = v0 - lse; o.y = v1 - lse;
        *(float2*)(out + (size_t)node * OUT_DIM + 2 * g) = o;
    }
}

extern "C" void kernel_launch(void* const* d_in, const int* in_sizes, int n_in,
                              void* d_out, int out_size, void* d_ws, size_t ws_size,
                              hipStream_t stream) {
    const float* x  = (const float*)d_in[0];
    const int*   ei = (const int*)d_in[1];
    const float* W1 = (const float*)d_in[2];
    const float* b1 = (const float*)d_in[3];
    const float* W2 = (const float*)d_in[4];
    const float* b2 = (const float*)d_in[5];
    float* out = (float*)d_out;

    const int n = N_NODES;
    const int e = E_EDGES;
    const int* srcp = ei;        // edge_index[0]
    const int* dstp = ei + e;    // edge_index[1]

    // workspace layout
    char* w = (char*)d_ws;
    int*      cnt_bb = (int*)w;        w += (size_t)NBUCK * NBLK * 4;
    int*      bbase  = (int*)w;        w += (size_t)(NBUCK + 1) * 4;
    int*      deg    = (int*)w;        w += (size_t)n * 4;
    int*      rowptr = (int*)w;        w += (size_t)(n + 1) * 4;
    float*    dinv   = (float*)w;      w += (size_t)n * 4;
    unsigned* tmp    = (unsigned*)w;   w += (size_t)e * 4;
    int*      ssrc   = (int*)w;        w += (size_t)e * 4;
    short*    w2t    = (short*)w;      w += (size_t)OUT_DIM * HID * 2;  // col-major bf16 W2
    short*    h1s    = (short*)w;      w += (size_t)n * HID * 2;     // bf16; scaled by K2
    short*    out1   = (short*)w;      w += (size_t)n * HID * 2;     // bf16 relu'd layer-1 out
    short*    h2s    = (short*)w;      w += (size_t)n * OUT_DIM * 2; // bf16

    auto blk = [](long long total, int b) { return (int)((total + b - 1) / b); };

    // K0: zero degree counters (tiny, before everything)
    hipMemsetAsync(deg, 0, (size_t)n * sizeof(int), stream);
    // K1: layer-1 GEMM (t=0 start, no CSR dep) || csr_a + deg atomics || w2t
    k1_gemm1_csra<<<GB1 + NBLK + 1, 512, 0, stream>>>(x, W1, (const int4*)dstp, W2,
                                                      cnt_bb, deg, w2t, h1s);
    // K2: bucket scatter (inline prefix; b1 folded) || h1s scale + dinv table
    k2_scatter_scale<<<NBLK + NCHUNK, 512, 0, stream>>>((const int4*)srcp,
                                                        (const int4*)dstp,
                                                        cnt_bb, deg, bbase,
                                                        dinv, h1s, tmp);
    // K3: within-bucket sort -> rowptr/ssrc
    csr_p2<<<NBUCK, 256, 0, stream>>>(tmp, bbase, rowptr, ssrc);
    // K4: layer-1 aggregate + bias/ReLU -> out1 (bf16)
    agg1_pull<<<blk(n, 4), 256, 0, stream>>>(h1s, dinv, b1, rowptr, ssrc, (uint4*)out1);
    // K5: layer-2 dense transform (MFMA), pre-scaled by dinv
    gemm2_mfma<<<blk(n, 64), 256, 0, stream>>>(out1, w2t, dinv, h2s);
    // K6: layer-2 aggregate + bias + log_softmax
    agg2_pull<<<blk(n, 4), 256, 0, stream>>>((const unsigned*)h2s, dinv, b2,
                                             rowptr, ssrc, out);
}

// Round 7
// 189.705 us; speedup vs baseline: 1.1737x; 1.1443x over previous
//
#include <hip/hip_runtime.h>
#include <hip/hip_bf16.h>

#define N_NODES 50000
#define E_EDGES 800000
#define IN_DIM  256
#define HID     128
#define OUT_DIM 16

#define NBUCK 391    // ceil(50000/128) buckets of 128 nodes (dst>>7)
#define NBLK  128    // blocks for bucket phases A/C
#define P2CAP 4096   // max edges per bucket (mean 2046, sigma ~45)
#define GB1   391    // gemm1 blocks: ceil(50000/128)

using frag_ab = __attribute__((ext_vector_type(8))) short;  // 8 bf16
using frag_cd = __attribute__((ext_vector_type(4))) float;  // 4 fp32

static __device__ inline short f2bf(float f) {
    union { float f; unsigned u; } v; v.f = f;
    unsigned r = (v.u + 0x7fffu + ((v.u >> 16) & 1u)) >> 16;
    return (short)r;
}
static __device__ inline float bflo(unsigned u) {
    union { unsigned u; float f; } v; v.u = u << 16; return v.f;
}
static __device__ inline float bfhi(unsigned u) {
    union { unsigned u; float f; } v; v.u = u & 0xffff0000u; return v.f;
}
static __device__ inline unsigned packbf(float a, float b) {
    return (unsigned)(unsigned short)f2bf(a) | ((unsigned)(unsigned short)f2bf(b) << 16);
}

// ===== K1: gemm1 (COALESCED W1 staging, UNSCALED h1s) || csr_a || w2t =======
// blocks [0, GB1): layer-1 dense transform, h1s = bf16(x @ W1)  (no dinv)
// blocks [GB1, GB1+NBLK): dst histogram into per-block bucket counts
// block  [GB1+NBLK]: W2 -> column-major bf16 (w2t[n][k])
__global__ __launch_bounds__(512) void k1_gemm1_csra(const float* __restrict__ x,
                                                     const float* __restrict__ W1,
                                                     const int4* __restrict__ dst4,
                                                     const float* __restrict__ W2,
                                                     int* __restrict__ cnt_bb,
                                                     short* __restrict__ w2t,
                                                     short* __restrict__ h1s) {
    __shared__ uint4 lwt[64 * 64];   // 64 KB (aliased as int hist[] for csr_a blocks)
    int tid = threadIdx.x;

    if (blockIdx.x == GB1 + NBLK) {
        // ---- w2t: W2 [128x16] f32 -> col-major bf16 [16][128]
        int n0 = tid >> 5, k0 = (tid & 31) * 4;
#pragma unroll
        for (int i = 0; i < 4; ++i)
            w2t[n0 * HID + k0 + i] = f2bf(W2[(k0 + i) * OUT_DIM + n0]);
        return;
    }
    if (blockIdx.x >= GB1) {
        // ---- csr_a: bucket histogram (512-thread partition; csr_c2 must match!)
        int* hist = (int*)lwt;
        int bb = blockIdx.x - GB1;
        for (int i = tid; i < NBUCK; i += 512) hist[i] = 0;
        __syncthreads();
        for (int i = bb * 512 + tid; i < E_EDGES / 4; i += NBLK * 512) {
            int4 d = dst4[i];
            atomicAdd(&hist[d.x >> 7], 1);
            atomicAdd(&hist[d.y >> 7], 1);
            atomicAdd(&hist[d.z >> 7], 1);
            atomicAdd(&hist[d.w >> 7], 1);
        }
        __syncthreads();
        for (int i = tid; i < NBUCK; i += 512) cnt_bb[i * NBLK + bb] = hist[i];
        return;
    }

    // ---- gemm1: COALESCED W1 -> fragment-major bf16 LDS tile.
    // Fragment layout (u32 view): element k = kt*32 + q*8 + 2*ip + lohi,
    // c = tt*16 + m  lives at  lds32[4*((kt*8+tt)*64 + q*16 + m) + ip],
    // low half = even k, high = odd k.
    // Pair-index p in [0,4096): k = 2*(p>>5) (128 even-k rows), c4 = (p&31)*4
    // (32 column quads). 4096 p * 4 u32 writes = 16384 u32 = full 64KB tile,
    // each (k-pair, c) exactly once.  COVERAGE VERIFIED (r6 bug: g<4 halved K).
    {
        unsigned* lds32 = (unsigned*)lwt;
#pragma unroll
        for (int g = 0; g < 8; ++g) {
            int p = g * 512 + tid;
            int k = (p >> 5) * 2;
            int c4 = (p & 31) * 4;
            float4 A = *(const float4*)(W1 + (size_t)k * HID + c4);
            float4 B = *(const float4*)(W1 + (size_t)(k + 1) * HID + c4);
            int kt = k >> 5, q = (k >> 3) & 3, ip = (k >> 1) & 3;
            float av[4] = {A.x, A.y, A.z, A.w};
            float bv[4] = {B.x, B.y, B.z, B.w};
#pragma unroll
            for (int i = 0; i < 4; ++i) {
                int c = c4 + i;
                int tt = c >> 4, m = c & 15;
                lds32[4 * (((kt * 8 + tt) << 6) + (q << 4) + m) + ip] = packbf(av[i], bv[i]);
            }
        }
    }

    int wave = tid >> 6;
    int lane = tid & 63;
    int m = lane & 15;
    int q = lane >> 4;
    int row0 = blockIdx.x * 128 + wave * 16;
    int arow_idx = row0 + m;
    const float4* arow4 = (const float4*)(x + (size_t)(arow_idx < N_NODES ? arow_idx : 0) * IN_DIM);

    frag_ab a[8];
#pragma unroll
    for (int kt = 0; kt < 8; ++kt) {
        float4 f0 = arow4[kt * 8 + q * 2];
        float4 f1 = arow4[kt * 8 + q * 2 + 1];
        a[kt][0] = f2bf(f0.x); a[kt][1] = f2bf(f0.y); a[kt][2] = f2bf(f0.z); a[kt][3] = f2bf(f0.w);
        a[kt][4] = f2bf(f1.x); a[kt][5] = f2bf(f1.y); a[kt][6] = f2bf(f1.z); a[kt][7] = f2bf(f1.w);
    }

    frag_cd acc[8];
#pragma unroll
    for (int t = 0; t < 8; ++t) acc[t] = frag_cd{0.f, 0.f, 0.f, 0.f};

    __syncthreads();

#pragma unroll
    for (int kt = 0; kt < 8; ++kt) {
#pragma unroll
        for (int t = 0; t < 8; ++t) {
            frag_ab b = *(const frag_ab*)&lwt[(kt * 8 + t) * 64 + lane];
            acc[t] = __builtin_amdgcn_mfma_f32_16x16x32_bf16(a[kt], b, acc[t], 0, 0, 0);
        }
    }

#pragma unroll
    for (int t = 0; t < 8; ++t) {
#pragma unroll
        for (int r = 0; r < 4; ++r) {
            int orow = row0 + q * 4 + r;
            if (orow < N_NODES)
                h1s[(size_t)orow * HID + t * 16 + m] = f2bf(acc[t][r]);   // unscaled
        }
    }
}

// ========== K2: per-bucket exclusive scan over blocks (proven r2) ===========
__global__ __launch_bounds__(NBLK) void csr_b1(int* __restrict__ cnt_bb,
                                               int* __restrict__ btot) {
    __shared__ int sm[NBLK];
    int b = blockIdx.x, t = threadIdx.x;
    int v = cnt_bb[b * NBLK + t];
    sm[t] = v;
    __syncthreads();
    for (int o = 1; o < NBLK; o <<= 1) {
        int u = (t >= o) ? sm[t - o] : 0;
        __syncthreads();
        sm[t] += u;
        __syncthreads();
    }
    cnt_bb[b * NBLK + t] = sm[t] - v;
    if (t == NBLK - 1) btot[b] = sm[t];
}

// ========== K3: csr_c with inline bucket-base scan (proven r2) ==============
__global__ __launch_bounds__(512) void csr_c2(const int4* __restrict__ src4,
                                              const int4* __restrict__ dst4,
                                              const int* __restrict__ cnt_bb,
                                              const int* __restrict__ btot,
                                              int* __restrict__ bbase,
                                              unsigned* __restrict__ tmp) {
    __shared__ int run[NBUCK];
    __shared__ int sc[512];
    int t = threadIdx.x;
    int v = (t < NBUCK) ? btot[t] : 0;
    sc[t] = v;
    __syncthreads();
    for (int o = 1; o < 512; o <<= 1) {
        int u = (t >= o) ? sc[t - o] : 0;
        __syncthreads();
        sc[t] += u;
        __syncthreads();
    }
    if (t < NBUCK) {
        int exc = sc[t] - v;
        run[t] = exc + cnt_bb[t * NBLK + blockIdx.x];
        if (blockIdx.x == 0) bbase[t] = exc;
    }
    if (blockIdx.x == 0 && t == 511) bbase[NBUCK] = sc[511];
    __syncthreads();
    for (int i = blockIdx.x * 512 + t; i < E_EDGES / 4; i += NBLK * 512) {
        int4 d = dst4[i];
        int4 s = src4[i];
        int p0 = atomicAdd(&run[d.x >> 7], 1);
        tmp[p0] = (unsigned)s.x | ((unsigned)(d.x & 127) << 17);
        int p1 = atomicAdd(&run[d.y >> 7], 1);
        tmp[p1] = (unsigned)s.y | ((unsigned)(d.y & 127) << 17);
        int p2 = atomicAdd(&run[d.z >> 7], 1);
        tmp[p2] = (unsigned)s.z | ((unsigned)(d.z & 127) << 17);
        int p3 = atomicAdd(&run[d.w >> 7], 1);
        tmp[p3] = (unsigned)s.w | ((unsigned)(d.w & 127) << 17);
    }
}

// ===== K4: within-bucket counting sort -> rowptr/dinv/ssrc + scale h1s ======
__global__ __launch_bounds__(256) void csr_p2s(const unsigned* __restrict__ tmp,
                                               const int* __restrict__ bbase,
                                               int* __restrict__ rowptr,
                                               float* __restrict__ dinv,
                                               int* __restrict__ ssrc,
                                               short* __restrict__ h1s) {
    __shared__ unsigned ed[P2CAP];
    __shared__ int cnt[128];
    __shared__ int off[128];
    __shared__ float sdv[128];
    int b = blockIdx.x, t = threadIdx.x;
    int base = bbase[b];
    int m = bbase[b + 1] - base;
    if (m > P2CAP) m = P2CAP;
    if (t < 128) cnt[t] = 0;
    __syncthreads();
    for (int i = t; i < m; i += 256) {
        unsigned v = tmp[base + i];
        ed[i] = v;
        atomicAdd(&cnt[v >> 17], 1);
    }
    __syncthreads();
    if (t < 128) off[t] = cnt[t];
    __syncthreads();
    for (int o = 1; o < 128; o <<= 1) {
        int u = (t >= o && t < 128) ? off[t - o] : 0;
        __syncthreads();
        if (t < 128) off[t] += u;
        __syncthreads();
    }
    if (t < 128) {
        int node = b * 128 + t;
        int ex = off[t] - cnt[t];
        float dv = rsqrtf((float)(cnt[t] + 1));
        sdv[t] = dv;
        if (node < N_NODES) {
            rowptr[node] = base + ex;
            dinv[node] = dv;
        }
        off[t] = ex;
    }
    if (b == NBUCK - 1 && t == 0) rowptr[N_NODES] = E_EDGES;
    __syncthreads();
    for (int i = t; i < m; i += 256) {
        unsigned v = ed[i];
        int p = atomicAdd(&off[v >> 17], 1);
        ssrc[base + p] = (int)(v & 0x1FFFF);
    }
    // scale h1s rows for this bucket's nodes: row *= dinv[node]
    for (int idx = t; idx < 128 * 16; idx += 256) {
        int nl = idx >> 4;
        int wd = idx & 15;
        int node = b * 128 + nl;
        if (node < N_NODES) {
            uint4* p = (uint4*)(h1s + (size_t)node * HID) + wd;
            uint4 u = *p;
            float dv = sdv[nl];
            u.x = packbf(dv * bflo(u.x), dv * bfhi(u.x));
            u.y = packbf(dv * bflo(u.y), dv * bfhi(u.y));
            u.z = packbf(dv * bflo(u.z), dv * bfhi(u.z));
            u.w = packbf(dv * bflo(u.w), dv * bfhi(u.w));
            *p = u;
        }
    }
}

// ===== K5: layer-1 pull (PROVEN, byte-identical gather loop) ================
__global__ __launch_bounds__(256) void agg1_pull(const short* __restrict__ h1s,
                                                 const float* __restrict__ dinv,
                                                 const float* __restrict__ b1,
                                                 const int* __restrict__ rowptr,
                                                 const int* __restrict__ ssrc,
                                                 uint4* __restrict__ out1) {
    int wave = threadIdx.x >> 6;
    int lane = threadIdx.x & 63;
    int node = __builtin_amdgcn_readfirstlane(blockIdx.x * 4 + wave);
    if (node >= N_NODES) return;
    int eo = lane >> 4;       // edge slot in quad
    int g  = lane & 15;       // feature octet

    int lo = rowptr[node], hi = rowptr[node + 1];
    float dd = dinv[node];
    float a0 = 0.f, a1 = 0.f, a2 = 0.f, a3 = 0.f;
    float a4 = 0.f, a5 = 0.f, a6 = 0.f, a7 = 0.f;

    if (eo == 0) {   // self-loop row
        uint4 u = *(const uint4*)(h1s + (size_t)node * HID + g * 8);
        a0 = bflo(u.x); a1 = bfhi(u.x); a2 = bflo(u.y); a3 = bfhi(u.y);
        a4 = bflo(u.z); a5 = bfhi(u.z); a6 = bflo(u.w); a7 = bfhi(u.w);
    }

    int e = lo;
    for (; e + 16 <= hi; e += 16) {
        int s0 = ssrc[e + eo];
        int s1 = ssrc[e + 4 + eo];
        int s2 = ssrc[e + 8 + eo];
        int s3 = ssrc[e + 12 + eo];
        uint4 u0 = *(const uint4*)(h1s + (size_t)s0 * HID + g * 8);
        uint4 u1 = *(const uint4*)(h1s + (size_t)s1 * HID + g * 8);
        uint4 u2 = *(const uint4*)(h1s + (size_t)s2 * HID + g * 8);
        uint4 u3 = *(const uint4*)(h1s + (size_t)s3 * HID + g * 8);
        a0 += bflo(u0.x); a1 += bfhi(u0.x); a2 += bflo(u0.y); a3 += bfhi(u0.y);
        a4 += bflo(u0.z); a5 += bfhi(u0.z); a6 += bflo(u0.w); a7 += bfhi(u0.w);
        a0 += bflo(u1.x); a1 += bfhi(u1.x); a2 += bflo(u1.y); a3 += bfhi(u1.y);
        a4 += bflo(u1.z); a5 += bfhi(u1.z); a6 += bflo(u1.w); a7 += bfhi(u1.w);
        a0 += bflo(u2.x); a1 += bfhi(u2.x); a2 += bflo(u2.y); a3 += bfhi(u2.y);
        a4 += bflo(u2.z); a5 += bfhi(u2.z); a6 += bflo(u2.w); a7 += bfhi(u2.w);
        a0 += bflo(u3.x); a1 += bfhi(u3.x); a2 += bflo(u3.y); a3 += bfhi(u3.y);
        a4 += bflo(u3.z); a5 += bfhi(u3.z); a6 += bflo(u3.w); a7 += bfhi(u3.w);
    }
    for (; e + 4 <= hi; e += 4) {
        int s = ssrc[e + eo];
        uint4 u = *(const uint4*)(h1s + (size_t)s * HID + g * 8);
        a0 += bflo(u.x); a1 += bfhi(u.x); a2 += bflo(u.y); a3 += bfhi(u.y);
        a4 += bflo(u.z); a5 += bfhi(u.z); a6 += bflo(u.w); a7 += bfhi(u.w);
    }
    if (eo < hi - e) {
        int s = ssrc[e + eo];
        uint4 u = *(const uint4*)(h1s + (size_t)s * HID + g * 8);
        a0 += bflo(u.x); a1 += bfhi(u.x); a2 += bflo(u.y); a3 += bfhi(u.y);
        a4 += bflo(u.z); a5 += bfhi(u.z); a6 += bflo(u.w); a7 += bfhi(u.w);
    }

    a0 += __shfl_xor(a0, 16); a1 += __shfl_xor(a1, 16);
    a2 += __shfl_xor(a2, 16); a3 += __shfl_xor(a3, 16);
    a4 += __shfl_xor(a4, 16); a5 += __shfl_xor(a5, 16);
    a6 += __shfl_xor(a6, 16); a7 += __shfl_xor(a7, 16);
    a0 += __shfl_xor(a0, 32); a1 += __shfl_xor(a1, 32);
    a2 += __shfl_xor(a2, 32); a3 += __shfl_xor(a3, 32);
    a4 += __shfl_xor(a4, 32); a5 += __shfl_xor(a5, 32);
    a6 += __shfl_xor(a6, 32); a7 += __shfl_xor(a7, 32);

    if (eo == 0) {
        float4 bA = *(const float4*)(b1 + g * 8);
        float4 bB = *(const float4*)(b1 + g * 8 + 4);
        float o0 = fmaxf(fmaf(dd, a0, bA.x), 0.f);
        float o1 = fmaxf(fmaf(dd, a1, bA.y), 0.f);
        float o2 = fmaxf(fmaf(dd, a2, bA.z), 0.f);
        float o3 = fmaxf(fmaf(dd, a3, bA.w), 0.f);
        float o4 = fmaxf(fmaf(dd, a4, bB.x), 0.f);
        float o5 = fmaxf(fmaf(dd, a5, bB.y), 0.f);
        float o6 = fmaxf(fmaf(dd, a6, bB.z), 0.f);
        float o7 = fmaxf(fmaf(dd, a7, bB.w), 0.f);
        uint4 st;
        st.x = packbf(o0, o1); st.y = packbf(o2, o3);
        st.z = packbf(o4, o5); st.w = packbf(o6, o7);
        out1[(size_t)node * 16 + g] = st;
    }
}

// ===== K6: layer-2 transform via MFMA (proven, unchanged) ===================
__global__ __launch_bounds__(256) void gemm2_mfma(const short* __restrict__ out1,
                                                  const short* __restrict__ w2t,
                                                  const float* __restrict__ dinv,
                                                  short* __restrict__ h2s) {
    int wave = threadIdx.x >> 6;
    int lane = threadIdx.x & 63;
    int m = lane & 15;
    int q = lane >> 4;
    int row0 = blockIdx.x * 64 + wave * 16;
    int arow = row0 + m;
    if (arow >= N_NODES) arow = N_NODES - 1;   // clamp loads
    const short* ap = out1 + (size_t)arow * HID + q * 8;
    const short* bp = w2t + m * HID + q * 8;

    frag_cd acc = frag_cd{0.f, 0.f, 0.f, 0.f};
#pragma unroll
    for (int kt = 0; kt < 4; ++kt) {
        frag_ab a = *(const frag_ab*)(ap + kt * 32);
        frag_ab b = *(const frag_ab*)(bp + kt * 32);
        acc = __builtin_amdgcn_mfma_f32_16x16x32_bf16(a, b, acc, 0, 0, 0);
    }
#pragma unroll
    for (int r = 0; r < 4; ++r) {
        int row = row0 + q * 4 + r;
        if (row < N_NODES)
            h2s[(size_t)row * OUT_DIM + m] = f2bf(acc[r] * dinv[row]);
    }
}

// ===== K7: layer-2 pull + bias + log_softmax (proven, unchanged) ============
__global__ __launch_bounds__(256) void agg2_pull(const unsigned* __restrict__ h2s,
                                                 const float* __restrict__ dinv,
                                                 const float* __restrict__ b2,
                                                 const int* __restrict__ rowptr,
                                                 const int* __restrict__ ssrc,
                                                 float* __restrict__ out) {
    int wave = threadIdx.x >> 6;
    int lane = threadIdx.x & 63;
    int node = __builtin_amdgcn_readfirstlane(blockIdx.x * 4 + wave);
    if (node >= N_NODES) return;
    int eo = lane >> 3;
    int g  = lane & 7;

    int lo = rowptr[node], hi = rowptr[node + 1];
    float a0 = 0.f, a1 = 0.f;
    if (eo == 0) {
        unsigned u = h2s[(size_t)node * 8 + g];
        a0 = bflo(u); a1 = bfhi(u);
    }
    int e = lo;
    for (; e + 16 <= hi; e += 16) {
        int s0 = ssrc[e + eo];
        int s1 = ssrc[e + 8 + eo];
        unsigned u0 = h2s[(size_t)s0 * 8 + g];
        unsigned u1 = h2s[(size_t)s1 * 8 + g];
        a0 += bflo(u0); a1 += bfhi(u0);
        a0 += bflo(u1); a1 += bfhi(u1);
    }
    for (; e + 8 <= hi; e += 8) {
        int s = ssrc[e + eo];
        unsigned u = h2s[(size_t)s * 8 + g];
        a0 += bflo(u); a1 += bfhi(u);
    }
    if (eo < hi - e) {
        int s = ssrc[e + eo];
        unsigned u = h2s[(size_t)s * 8 + g];
        a0 += bflo(u); a1 += bfhi(u);
    }

    a0 += __shfl_xor(a0, 8);  a1 += __shfl_xor(a1, 8);
    a0 += __shfl_xor(a0, 16); a1 += __shfl_xor(a1, 16);
    a0 += __shfl_xor(a0, 32); a1 += __shfl_xor(a1, 32);

    float dd = dinv[node];
    float2 bb = *(const float2*)(b2 + 2 * g);
    float v0 = fmaf(dd, a0, bb.x);
    float v1 = fmaf(dd, a1, bb.y);

    float m = fmaxf(v0, v1);
#pragma unroll
    for (int msk = 1; msk < 8; msk <<= 1) m = fmaxf(m, __shfl_xor(m, msk));
    float s2 = __expf(v0 - m) + __expf(v1 - m);
#pragma unroll
    for (int msk = 1; msk < 8; msk <<= 1) s2 += __shfl_xor(s2, msk);
    float lse = m + __logf(s2);
    if (eo == 0) {
        float2 o; o.x = v0 - lse; o.y = v1 - lse;
        *(float2*)(out + (size_t)node * OUT_DIM + 2 * g) = o;
    }
}

extern "C" void kernel_launch(void* const* d_in, const int* in_sizes, int n_in,
                              void* d_out, int out_size, void* d_ws, size_t ws_size,
                              hipStream_t stream) {
    const float* x  = (const float*)d_in[0];
    const int*   ei = (const int*)d_in[1];
    const float* W1 = (const float*)d_in[2];
    const float* b1 = (const float*)d_in[3];
    const float* W2 = (const float*)d_in[4];
    const float* b2 = (const float*)d_in[5];
    float* out = (float*)d_out;

    const int n = N_NODES;
    const int e = E_EDGES;
    const int* srcp = ei;        // edge_index[0]
    const int* dstp = ei + e;    // edge_index[1]

    // workspace layout
    char* w = (char*)d_ws;
    int*      cnt_bb = (int*)w;        w += (size_t)NBUCK * NBLK * 4;
    int*      btot   = (int*)w;        w += (size_t)NBUCK * 4;
    int*      bbase  = (int*)w;        w += (size_t)(NBUCK + 1) * 4;
    int*      rowptr = (int*)w;        w += (size_t)(n + 1) * 4;
    float*    dinv   = (float*)w;      w += (size_t)n * 4;
    unsigned* tmp    = (unsigned*)w;   w += (size_t)e * 4;
    int*      ssrc   = (int*)w;        w += (size_t)e * 4;
    short*    w2t    = (short*)w;      w += (size_t)OUT_DIM * HID * 2;  // col-major bf16 W2
    short*    h1s    = (short*)w;      w += (size_t)n * HID * 2;     // bf16; scaled by csr_p2s
    short*    out1   = (short*)w;      w += (size_t)n * HID * 2;     // bf16 relu'd layer-1 out
    short*    h2s    = (short*)w;      w += (size_t)n * OUT_DIM * 2; // bf16

    auto blk = [](long long total, int b) { return (int)((total + b - 1) / b); };

    // K1: layer-1 GEMM (coalesced W1 staging) || csr_a || w2t
    k1_gemm1_csra<<<GB1 + NBLK + 1, 512, 0, stream>>>(x, W1, (const int4*)dstp, W2,
                                                      cnt_bb, w2t, h1s);
    // K2: per-bucket scan over blocks
    csr_b1<<<NBUCK, NBLK, 0, stream>>>(cnt_bb, btot);
    // K3: bucket scatter (inline bbase scan; block 0 publishes bbase)
    csr_c2<<<NBLK, 512, 0, stream>>>((const int4*)srcp, (const int4*)dstp,
                                     cnt_bb, btot, bbase, tmp);
    // K4: within-bucket sort -> rowptr/dinv/ssrc; scales h1s rows in place
    csr_p2s<<<NBUCK, 256, 0, stream>>>(tmp, bbase, rowptr, dinv, ssrc, h1s);
    // K5: layer-1 aggregate + bias/ReLU -> out1 (bf16)
    agg1_pull<<<blk(n, 4), 256, 0, stream>>>(h1s, dinv, b1, rowptr, ssrc, (uint4*)out1);
    // K6: layer-2 dense transform (MFMA), pre-scaled by dinv
    gemm2_mfma<<<blk(n, 64), 256, 0, stream>>>(out1, w2t, dinv, h2s);
    // K7: layer-2 aggregate + bias + log_softmax
    agg2_pull<<<blk(n, 4), 256, 0, stream>>>((const unsigned*)h2s, dinv, b2,
                                             rowptr, ssrc, out);
}